// Round 7
// baseline (435.574 us; speedup 1.0000x reference)
//
#include <hip/hip_runtime.h>
#include <hip/hip_bf16.h>

// ---------------------------------------------------------------------------
// concat(x1,x2) -> LSTM(551->128, T=5) -> MLP 640->531->256->64->2 -> softmax
// B=16384, T=5, IN=551, H=128. bf16 MFMA 16x16x32, fp32 accum.
// R9: R8 with the sync structure replaced by the 2-phase template (T3 minimum
//     + T14): per K-step ONE barrier; stage(s+1) issued BEFORE compute(s) so
//     the ~1000-cyc load latency hides under the LDS+MFMA phase; cvt+ds_write
//     after compute (write-late); WAITV(0)+LGKM0 then s_barrier. As/Bs double
//     buffered (32 KB). Tail (cols 548-551) handled by in-register shuffle of
//     an in-bounds x2 load (no W-shift hack).
//     Geometry unchanged from R8: BM=128 BN=128 BK=32, 256 thr, grid 2560
//     XCD-swizzled, chunk-XOR LDS swizzle (measured 0 conflicts), reg-staged
//     A (alignment-safe), B via global_load_lds. k2/mlp/prep unchanged.
// Packed B/A-tile layout: 16(n|m) x 32(k) tile = 512 elems, element
//   (n,k) -> tile(tn=n>>4, tk=k>>5) at offset lane*8+j, lane=((k>>3)&3)*16+(n&15), j=k&7.
// Packed C-tile layout: 16x16 tile = 256 elems, (m,n) -> offset lane*4+r,
//   lane=((m>>2)&3)*16+(n&15), r=m&3.
// ---------------------------------------------------------------------------

typedef short  short8  __attribute__((ext_vector_type(8)));
typedef short  short4v __attribute__((ext_vector_type(4)));
typedef float  f32x4   __attribute__((ext_vector_type(4)));

#define MFMA(a, b, c) __builtin_amdgcn_mfma_f32_16x16x32_bf16((a), (b), (c), 0, 0, 0)
#define WAITV(N) asm volatile("s_waitcnt vmcnt(" #N ")" ::: "memory")
#define LGKM0()  asm volatile("s_waitcnt lgkmcnt(0)" ::: "memory")
#define MEMF()   asm volatile("" ::: "memory")
#define BAR()    __builtin_amdgcn_s_barrier()

__device__ __forceinline__ short f2bs(float f) {
    __hip_bfloat16 h = __float2bfloat16(f);   // RNE
    union { __hip_bfloat16 h; short s; } u; u.h = h; return u.s;
}
__device__ __forceinline__ float b2f(short s) {
    union { unsigned u; float f; } v; v.u = ((unsigned)(unsigned short)s) << 16; return v.f;
}
__device__ __forceinline__ float sigf(float x)  { return 1.f / (1.f + __expf(-x)); }
__device__ __forceinline__ float mytanh(float x){ return 2.f / (1.f + __expf(-2.f * x)) - 1.f; }

// async global(16B) -> LDS; dest is wave-uniform base, HW adds lane*16
__device__ __forceinline__ void gload16(const void* g, void* l) {
    __builtin_amdgcn_global_load_lds(
        (const __attribute__((address_space(1))) void*)g,
        (__attribute__((address_space(3))) void*)l, 16, 0, 0);
}

// ---------------- constants ----------------
#define BB     16384
#define TT     5
#define F1     300
#define F2     251
#define INF    551
#define KP     576          // padded K for input GEMM (18 k-tiles)
#define G4     512
#define HH     128
#define FLAT   640          // T*H (20 k-tiles)
#define L1N    531
#define L1P    576
#define L1KP   544          // 17 k-tiles
#define L2N    256
#define L3N    64

// ws offsets (bytes)
#define O_WIH  0u
#define O_WHH  589824u
#define O_W1   720896u
#define O_W2   1458176u
#define O_W3   1736704u
#define O_BG   1769472u
#define O_B1   1771520u
#define O_XG   1773824u
#define O_HS   85659904u
#define WS_NEED 106631424u

// ---------------------------------------------------------------------------
// prep: weights fp32 -> bf16, packed in B-fragment tile order
// ---------------------------------------------------------------------------
__device__ __forceinline__ void pack_b(const float* __restrict__ W, short* __restrict__ dst,
                                       int i, int tpn, int Nsrc, int Ksrc, int ldw)
{
    int tile = i >> 9, rem = i & 511, lane = rem >> 3, jj = rem & 7;
    int tn = tile / tpn, tk = tile - tn * tpn;
    int n = tn * 16 + (lane & 15);
    int k = tk * 32 + (lane >> 4) * 8 + jj;
    float v = (n < Nsrc && k < Ksrc) ? W[n * ldw + k] : 0.f;
    dst[i] = f2bs(v);
}

__global__ void prep_kernel(
    const float* __restrict__ W_ih, const float* __restrict__ W_hh,
    const float* __restrict__ b_ih, const float* __restrict__ b_hh,
    const float* __restrict__ W1,   const float* __restrict__ b1,
    const float* __restrict__ W2,   const float* __restrict__ W3,
    short* __restrict__ Wihp, short* __restrict__ Whhp, float* __restrict__ biasg,
    short* __restrict__ W1p,  float* __restrict__ b1p,  short* __restrict__ W2p,
    short* __restrict__ W3p)
{
    const int N0 = G4 * KP;            // 294912
    const int N1 = N0 + G4 * HH;       // +65536
    const int N2 = N1 + L1P * FLAT;    // +368640
    const int N3 = N2 + L2N * L1KP;    // +139264
    const int N4 = N3 + L3N * L2N;     // +16384
    const int N5 = N4 + G4;
    const int N6 = N5 + L1P;
    const int stride = gridDim.x * blockDim.x;
    for (int i = blockIdx.x * blockDim.x + threadIdx.x; i < N6; i += stride) {
        if (i < N0)      pack_b(W_ih, Wihp, i,       18, G4,  INF, INF);
        else if (i < N1) pack_b(W_hh, Whhp, i - N0,   4, G4,  HH,  HH);
        else if (i < N2) pack_b(W1,   W1p,  i - N1,  20, L1N, FLAT, FLAT);
        else if (i < N3) pack_b(W2,   W2p,  i - N2,  17, L2N, L1N, L1N);
        else if (i < N4) pack_b(W3,   W3p,  i - N3,   8, L3N, L2N, L2N);
        else if (i < N5) { int j = i - N4; biasg[j] = b_ih[j] + b_hh[j]; }
        else             { int j = i - N5; b1p[j] = (j < L1N) ? b1[j] : 0.f; }
    }
}

// ---------------------------------------------------------------------------
// per-float4 concat select (4B-aligned-safe; boundary 300 is 4-aligned so
// no float4 straddles x1/x2). Valid for c <= 544.
// ---------------------------------------------------------------------------
__device__ __forceinline__ float4 ld4r(const float* __restrict__ x1r,
                                       const float* __restrict__ x2r, int c)
{
    const float* p = (c < F1) ? (x1r + c) : (x2r + (c - F1));
    return *(const float4*)p;
}

// ---------------------------------------------------------------------------
// k1_xgemm: xg = concat(x)@W_ih^T + bias.  2-phase single-barrier pipeline.
// Grid 2560 = 640 m-panels x 4 n-blocks(gates), XCD-swizzled.
// Block: 256 thr (4 waves, wave (wm,wn) = 2x2), BM=128 BN=128 BK=32.
// Per K-step: stage B(s+1) DMA + A(s+1) reg loads; compute(s) (ds_read +
// 16 MFMA/wave); cvt+ds_write A(s+1); WAITV(0); LGKM0; BAR.  Load latency
// hides under compute; one barrier per step.
// ---------------------------------------------------------------------------
__global__ __launch_bounds__(256, 3) void k1_xgemm(
    const float* __restrict__ x1, const float* __restrict__ x2,
    const short* __restrict__ Wihp, const float* __restrict__ biasg,
    short* __restrict__ xg)
{
    __shared__ __align__(16) short As[2][128][32];   // 16 KB bf16, chunk-swizzled
    __shared__ __align__(16) short Bs[2][8][512];    // 16 KB packed B tiles
    const int tid  = threadIdx.x;
    const int w    = tid >> 6;
    const int lane = tid & 63;
    const int c16  = lane & 15;
    const int kq   = lane >> 4;          // 0..3 (A chunk to read)
    const int wm   = w >> 1, wn = w & 1;

    // XCD-swizzled mapping
    const int id  = blockIdx.x;
    const int mp  = (id & 7) * 80 + ((id >> 3) >> 2);   // m-panel 0..639
    const int nb  = (id >> 3) & 3;                      // gate / n-block
    const int m0  = mp * 128;
    const int t   = m0 >> 14;
    const int bb  = m0 & 16383;

    // A staging: thread -> row sr = tid>>1, half sh = tid&1 (cols 16sh..16sh+15)
    const int sr = tid >> 1, sh = tid & 1;
    const int arow = bb + sr;
    const float* x1r = x1 + ((size_t)arow * TT + t) * F1;
    const float* x2r = x2 + ((size_t)arow * TT + t) * F2;
    const int fA  = (sr >> 1) & 3;                      // row swizzle field
    const int ch0 = ((sh << 1)    ) ^ fA;               // dest chunk for q0q1
    const int ch1 = ((sh << 1) | 1) ^ fA;               // dest chunk for q2q3

    f32x4 acc[4][4];
#pragma unroll
    for (int mt = 0; mt < 4; ++mt)
#pragma unroll
        for (int nt = 0; nt < 4; ++nt)
            acc[mt][nt] = (f32x4){0.f, 0.f, 0.f, 0.f};

    // ---- prologue: stage step 0 into buf 0 ----
    {
#pragma unroll
        for (int i2 = 0; i2 < 2; ++i2) {
            int tnl = w * 2 + i2;
            gload16(Wihp + (((nb * 8 + tnl) * 18 + 0) << 9) + lane * 8,
                    &Bs[0][tnl][0]);
        }
        int c0 = sh * 16;
        float4 q0 = ld4r(x1r, x2r, c0);
        float4 q1 = ld4r(x1r, x2r, c0 + 4);
        float4 q2 = ld4r(x1r, x2r, c0 + 8);
        float4 q3 = ld4r(x1r, x2r, c0 + 12);
        short8 v0, v1;
        v0[0]=f2bs(q0.x); v0[1]=f2bs(q0.y); v0[2]=f2bs(q0.z); v0[3]=f2bs(q0.w);
        v0[4]=f2bs(q1.x); v0[5]=f2bs(q1.y); v0[6]=f2bs(q1.z); v0[7]=f2bs(q1.w);
        v1[0]=f2bs(q2.x); v1[1]=f2bs(q2.y); v1[2]=f2bs(q2.z); v1[3]=f2bs(q2.w);
        v1[4]=f2bs(q3.x); v1[5]=f2bs(q3.y); v1[6]=f2bs(q3.z); v1[7]=f2bs(q3.w);
        *(short8*)&As[0][sr][ch0 << 3] = v0;
        *(short8*)&As[0][sr][ch1 << 3] = v1;
    }
    WAITV(0); LGKM0(); BAR(); MEMF();

    // ---- main loop: s = 0..16, stage s+1 under compute(s), 1 barrier ----
    for (int s = 0; s < 17; ++s) {
        const int nbuf = (s + 1) & 1, cbuf = s & 1;

        // stage B(s+1): async DMA (vmcnt)
#pragma unroll
        for (int i2 = 0; i2 < 2; ++i2) {
            int tnl = w * 2 + i2;
            gload16(Wihp + (((nb * 8 + tnl) * 18 + (s + 1)) << 9) + lane * 8,
                    &Bs[nbuf][tnl][0]);
        }
        // issue A(s+1) reg loads (latency overlaps compute below)
        float4 q0, q1, q2, q3;
        if (s + 1 < 17) {
            int c0 = (s + 1) * 32 + sh * 16;   // <= 540
            q0 = ld4r(x1r, x2r, c0);
            q1 = ld4r(x1r, x2r, c0 + 4);
            q2 = ld4r(x1r, x2r, c0 + 8);
            q3 = ld4r(x1r, x2r, c0 + 12);
        } else {
            if (sh == 0) {
                q0 = *(const float4*)(x2r + 244);          // cols 544..547
                float4 qt = *(const float4*)(x2r + 247);   // x[547..550]
                q1 = (float4){qt.y, qt.z, qt.w, 0.f};      // cols 548,549,550,pad
            } else {
                q0 = (float4){0.f, 0.f, 0.f, 0.f};
                q1 = q0;
            }
            q2 = (float4){0.f, 0.f, 0.f, 0.f};             // k >= 552: W = 0
            q3 = q2;
        }

        // compute(s) from buf cbuf
        {
            short8 a[4];
#pragma unroll
            for (int mt = 0; mt < 4; ++mt) {
                int r = (wm * 4 + mt) * 16 + c16;
                a[mt] = *(const short8*)&As[cbuf][r][(kq ^ ((r >> 1) & 3)) << 3];
            }
#pragma unroll
            for (int nt = 0; nt < 4; ++nt) {
                short8 b = *(const short8*)&Bs[cbuf][wn * 4 + nt][lane * 8];
#pragma unroll
                for (int mt = 0; mt < 4; ++mt)
                    acc[mt][nt] = MFMA(a[mt], b, acc[mt][nt]);
            }
        }

        // cvt + ds_write A(s+1) (write-late; compiler waits q* via vmcnt)
        {
            short8 v0, v1;
            v0[0]=f2bs(q0.x); v0[1]=f2bs(q0.y); v0[2]=f2bs(q0.z); v0[3]=f2bs(q0.w);
            v0[4]=f2bs(q1.x); v0[5]=f2bs(q1.y); v0[6]=f2bs(q1.z); v0[7]=f2bs(q1.w);
            v1[0]=f2bs(q2.x); v1[1]=f2bs(q2.y); v1[2]=f2bs(q2.z); v1[3]=f2bs(q2.w);
            v1[4]=f2bs(q3.x); v1[5]=f2bs(q3.y); v1[6]=f2bs(q3.z); v1[7]=f2bs(q3.w);
            *(short8*)&As[nbuf][sr][ch0 << 3] = v0;
            *(short8*)&As[nbuf][sr][ch1 << 3] = v1;
        }
        WAITV(0); LGKM0(); BAR(); MEMF();
    }

    // ---- final step 17 (buf 1), no staging ----
    {
        short8 a[4];
#pragma unroll
        for (int mt = 0; mt < 4; ++mt) {
            int r = (wm * 4 + mt) * 16 + c16;
            a[mt] = *(const short8*)&As[1][r][(kq ^ ((r >> 1) & 3)) << 3];
        }
#pragma unroll
        for (int nt = 0; nt < 4; ++nt) {
            short8 b = *(const short8*)&Bs[1][wn * 4 + nt][lane * 8];
#pragma unroll
            for (int mt = 0; mt < 4; ++mt)
                acc[mt][nt] = MFMA(a[mt], b, acc[mt][nt]);
        }
    }

    // ---- epilogue: +bias, packed C-tile store (8B/lane, coalesced) ----
#pragma unroll
    for (int nt = 0; nt < 4; ++nt) {
        int tn = nb * 8 + wn * 4 + nt;
        float bv = biasg[tn * 16 + c16];
#pragma unroll
        for (int mt = 0; mt < 4; ++mt) {
            short4v o;
#pragma unroll
            for (int r = 0; r < 4; ++r) o[r] = f2bs(acc[mt][nt][r] + bv);
            int tm = (m0 >> 4) + wm * 4 + mt;
            *(short4v*)&xg[((tm * 32 + tn) << 8) + lane * 4] = o;
        }
    }
}

// ---------------------------------------------------------------------------
// k2_rec: fused LSTM recurrence, 32 samples/block, 512 blocks, 512 thr.
// W_hh B-frags in registers (reused all t). xg read as packed C-tiles (8B/lane).
// h round-trips through LDS; hs exported in packed A-tile layout (16B/lane).
// ---------------------------------------------------------------------------
__global__ __launch_bounds__(512, 2) void k2_rec(
    const short* __restrict__ Whhp, const short* __restrict__ xg,
    short* __restrict__ hs)
{
    __shared__ __align__(16) short hb[2][32][136];
    const int tid  = threadIdx.x;
    const int w    = tid >> 6;
    const int lane = tid & 63;
    const int quad = lane >> 4;
    const int c16  = lane & 15;
    const int btile = blockIdx.x * 2;       // sample-tile base (32 samples)

    short8 bfr[4][4];                       // [gate][ks]
#pragma unroll
    for (int g = 0; g < 4; ++g)
#pragma unroll
        for (int ks = 0; ks < 4; ++ks)
            bfr[g][ks] = *(const short8*)&Whhp[((((g * 8 + w) * 4) + ks) << 9) + lane * 8];

    float cst[2][4];
#pragma unroll
    for (int mt = 0; mt < 2; ++mt)
#pragma unroll
        for (int r = 0; r < 4; ++r) cst[mt][r] = 0.f;

    const int j = w * 16 + c16;

    for (int t = 0; t < TT; ++t) {
        short4v xq[2][4];
#pragma unroll
        for (int mt = 0; mt < 2; ++mt)
#pragma unroll
            for (int g = 0; g < 4; ++g)
                xq[mt][g] = *(const short4v*)
                    &xg[((((t << 10) + btile + mt) * 32 + (g * 8 + w)) << 8) + lane * 4];

        f32x4 acc[2][4];
#pragma unroll
        for (int mt = 0; mt < 2; ++mt)
#pragma unroll
            for (int g = 0; g < 4; ++g)
                acc[mt][g] = (f32x4){0.f, 0.f, 0.f, 0.f};

        if (t > 0) {
            const short (*cur)[136] = hb[(t - 1) & 1];
#pragma unroll
            for (int ks = 0; ks < 4; ++ks) {
                short8 a[2];
#pragma unroll
                for (int mt = 0; mt < 2; ++mt)
                    a[mt] = *(const short8*)&cur[mt * 16 + c16][ks * 32 + quad * 8];
#pragma unroll
                for (int mt = 0; mt < 2; ++mt)
#pragma unroll
                    for (int g = 0; g < 4; ++g)
                        acc[mt][g] = MFMA(a[mt], bfr[g][ks], acc[mt][g]);
            }
        }

        short (*nxt)[136] = hb[t & 1];
#pragma unroll
        for (int mt = 0; mt < 2; ++mt) {
#pragma unroll
            for (int r = 0; r < 4; ++r) {
                int m = mt * 16 + quad * 4 + r;
                float gi = acc[mt][0][r] + b2f(xq[mt][0][r]);
                float gf = acc[mt][1][r] + b2f(xq[mt][1][r]);
                float gg = acc[mt][2][r] + b2f(xq[mt][2][r]);
                float go = acc[mt][3][r] + b2f(xq[mt][3][r]);
                float cn = sigf(gf) * cst[mt][r] + sigf(gi) * mytanh(gg);
                cst[mt][r] = cn;
                nxt[m][j] = f2bs(sigf(go) * mytanh(cn));
            }
        }
        __syncthreads();
        {
            int tm = w >> 2, kt = w & 3;
            short8 v = *(const short8*)&nxt[tm * 16 + c16][kt * 32 + quad * 8];
            *(short8*)&hs[(((btile + tm) * 20 + t * 4 + kt) << 9) + lane * 8] = v;
        }
    }
}

// ---------------------------------------------------------------------------
// mlp: fused 640->576(531)->256->64->2 + softmax. 32 samples/block, 256 thr.
// hs read as packed A-tiles; weights as packed B-tiles (all 16B/lane).
// ---------------------------------------------------------------------------
__global__ __launch_bounds__(256, 2) void mlp_kernel(
    const short* __restrict__ hs,
    const short* __restrict__ W1p, const float* __restrict__ b1p,
    const short* __restrict__ W2p, const float* __restrict__ b2,
    const short* __restrict__ W3p, const float* __restrict__ b3,
    const float* __restrict__ W4,  const float* __restrict__ b4,
    float* __restrict__ out)
{
    __shared__ __align__(16) short a1[32][584];
    __shared__ __align__(16) short a2[32][264];
    __shared__ __align__(16) short a3[32][72];
    const int tid  = threadIdx.x;
    const int w    = tid >> 6;
    const int lane = tid & 63;
    const int quad = lane >> 4;
    const int c16  = lane & 15;
    const int m0   = blockIdx.x * 32;
    const int mtile = blockIdx.x * 2;

    {
        f32x4 acc[2][9];
#pragma unroll
        for (int mt = 0; mt < 2; ++mt)
#pragma unroll
            for (int i = 0; i < 9; ++i)
                acc[mt][i] = (f32x4){0.f, 0.f, 0.f, 0.f};
#pragma unroll 4
        for (int ks = 0; ks < 20; ++ks) {
            short8 a[2];
#pragma unroll
            for (int mt = 0; mt < 2; ++mt)
                a[mt] = *(const short8*)&hs[(((mtile + mt) * 20 + ks) << 9) + lane * 8];
#pragma unroll
            for (int i = 0; i < 9; ++i) {
                short8 b = *(const short8*)&W1p[(((w * 9 + i) * 20 + ks) << 9) + lane * 8];
                acc[0][i] = MFMA(a[0], b, acc[0][i]);
                acc[1][i] = MFMA(a[1], b, acc[1][i]);
            }
        }
#pragma unroll
        for (int i = 0; i < 9; ++i) {
            int n = (w * 9 + i) * 16 + c16;
            float bv = b1p[n];
#pragma unroll
            for (int mt = 0; mt < 2; ++mt)
#pragma unroll
                for (int r = 0; r < 4; ++r) {
                    int m = mt * 16 + quad * 4 + r;
                    float v = acc[mt][i][r] + bv;
                    a1[m][n] = f2bs(v > 0.f ? v : 0.f);
                }
        }
    }
    __syncthreads();

    {
        f32x4 acc[2][4];
#pragma unroll
        for (int mt = 0; mt < 2; ++mt)
#pragma unroll
            for (int i = 0; i < 4; ++i)
                acc[mt][i] = (f32x4){0.f, 0.f, 0.f, 0.f};
#pragma unroll 4
        for (int ks = 0; ks < 17; ++ks) {
            short8 a[2];
#pragma unroll
            for (int mt = 0; mt < 2; ++mt)
                a[mt] = *(const short8*)&a1[mt * 16 + c16][ks * 32 + quad * 8];
#pragma unroll
            for (int i = 0; i < 4; ++i) {
                short8 b = *(const short8*)&W2p[(((w * 4 + i) * 17 + ks) << 9) + lane * 8];
                acc[0][i] = MFMA(a[0], b, acc[0][i]);
                acc[1][i] = MFMA(a[1], b, acc[1][i]);
            }
        }
#pragma unroll
        for (int i = 0; i < 4; ++i) {
            int n = (w * 4 + i) * 16 + c16;
            float bv = b2[n];
#pragma unroll
            for (int mt = 0; mt < 2; ++mt)
#pragma unroll
                for (int r = 0; r < 4; ++r) {
                    int m = mt * 16 + quad * 4 + r;
                    float v = acc[mt][i][r] + bv;
                    a2[m][n] = f2bs(v > 0.f ? v : 0.f);
                }
        }
    }
    __syncthreads();

    {
        f32x4 acc[2];
        acc[0] = (f32x4){0.f, 0.f, 0.f, 0.f};
        acc[1] = (f32x4){0.f, 0.f, 0.f, 0.f};
#pragma unroll
        for (int ks = 0; ks < 8; ++ks) {
            short8 a[2];
#pragma unroll
            for (int mt = 0; mt < 2; ++mt)
                a[mt] = *(const short8*)&a2[mt * 16 + c16][ks * 32 + quad * 8];
            short8 b = *(const short8*)&W3p[((w * 8 + ks) << 9) + lane * 8];
            acc[0] = MFMA(a[0], b, acc[0]);
            acc[1] = MFMA(a[1], b, acc[1]);
        }
        int n = w * 16 + c16;
        float bv = b3[n];
#pragma unroll
        for (int mt = 0; mt < 2; ++mt)
#pragma unroll
            for (int r = 0; r < 4; ++r) {
                int m = mt * 16 + quad * 4 + r;
                float v = acc[mt][r] + bv;
                a3[m][n] = f2bs(v > 0.f ? v : 0.f);
            }
    }
    __syncthreads();

    if (tid < 64) {
        int m   = tid >> 1;
        int cls = tid & 1;
        float s = b4[cls];
#pragma unroll 8
        for (int k = 0; k < 64; ++k)
            s += b2f(a3[m][k]) * W4[cls * 64 + k];
        float other = __shfl_xor(s, 1);
        float p = 1.f / (1.f + __expf(other - s));
        out[(m0 + m) * 2 + cls] = p;
    }
}

// ---------------------------------------------------------------------------
extern "C" void kernel_launch(void* const* d_in, const int* in_sizes, int n_in,
                              void* d_out, int out_size, void* d_ws, size_t ws_size,
                              hipStream_t stream)
{
    (void)in_sizes; (void)n_in; (void)out_size;
    if (ws_size < (size_t)WS_NEED) return;

    const float* x1   = (const float*)d_in[0];
    const float* x2   = (const float*)d_in[1];
    const float* W_ih = (const float*)d_in[2];
    const float* W_hh = (const float*)d_in[3];
    const float* b_ih = (const float*)d_in[4];
    const float* b_hh = (const float*)d_in[5];
    const float* W1   = (const float*)d_in[6];
    const float* b1   = (const float*)d_in[7];
    const float* W2   = (const float*)d_in[8];
    const float* b2   = (const float*)d_in[9];
    const float* W3   = (const float*)d_in[10];
    const float* b3   = (const float*)d_in[11];
    const float* W4   = (const float*)d_in[12];
    const float* b4   = (const float*)d_in[13];

    char* ws = (char*)d_ws;
    short* Wihp  = (short*)(ws + O_WIH);
    short* Whhp  = (short*)(ws + O_WHH);
    short* W1p   = (short*)(ws + O_W1);
    short* W2p   = (short*)(ws + O_W2);
    short* W3p   = (short*)(ws + O_W3);
    float* biasg = (float*)(ws + O_BG);
    float* b1p   = (float*)(ws + O_B1);
    short* xg    = (short*)(ws + O_XG);
    short* hsb   = (short*)(ws + O_HS);

    prep_kernel<<<3461, 256, 0, stream>>>(W_ih, W_hh, b_ih, b_hh, W1, b1, W2, W3,
                                          Wihp, Whhp, biasg, W1p, b1p, W2p, W3p);
    k1_xgemm<<<2560, 256, 0, stream>>>(x1, x2, Wihp, biasg, xg);
    k2_rec<<<512, 512, 0, stream>>>(Whhp, xg, hsb);
    mlp_kernel<<<512, 256, 0, stream>>>(hsb, W1p, b1p, W2p, b2, W3p, b3, W4, b4,
                                        (float*)d_out);
}

// Round 8
// 398.976 us; speedup vs baseline: 1.0917x; 1.0917x over previous
//
#include <hip/hip_runtime.h>
#include <hip/hip_bf16.h>

// ---------------------------------------------------------------------------
// concat(x1,x2) -> LSTM(551->128, T=5) -> MLP 640->531->256->64->2 -> softmax
// B=16384, T=5, IN=551, H=128. bf16 MFMA 16x16x32, fp32 accum.
// R10: stop-loss + traffic cut.
//   k1_xgemm: restored to R0 verbatim (best measured, 127.4 us): half-K LDS
//             staging, 4 barriers total, BM=64 BN=512, 512 thr, grid 1280.
//   k2mlp:    k2_rec + mlp merged in one 512-thr kernel; hs lives in LDS
//             (40 KB), never touches HBM (-164 MB round-trip). Phase 2 is
//             R6's verified 8-wave MLP (mh x wn), layers from LDS union:
//             region0 hsL(40KB)|a2, region1 hb(17.4)|a1(37.4)|a3. 76.5 KB
//             -> 2 blocks/CU.
// Packed B/A-tile layout: 16(n|m) x 32(k) tile = 512 elems, element
//   (n,k) -> tile(tn=n>>4, tk=k>>5) at offset lane*8+j, lane=((k>>3)&3)*16+(n&15), j=k&7.
// Packed C-tile layout: 16x16 tile = 256 elems, (m,n) -> offset lane*4+r,
//   lane=((m>>2)&3)*16+(n&15), r=m&3.   (matches MFMA C layout per lane)
// ---------------------------------------------------------------------------

typedef short  short8  __attribute__((ext_vector_type(8)));
typedef short  short4v __attribute__((ext_vector_type(4)));
typedef float  f32x4   __attribute__((ext_vector_type(4)));

#define MFMA(a, b, c) __builtin_amdgcn_mfma_f32_16x16x32_bf16((a), (b), (c), 0, 0, 0)

__device__ __forceinline__ short f2bs(float f) {
    __hip_bfloat16 h = __float2bfloat16(f);   // RNE
    union { __hip_bfloat16 h; short s; } u; u.h = h; return u.s;
}
__device__ __forceinline__ float b2f(short s) {
    union { unsigned u; float f; } v; v.u = ((unsigned)(unsigned short)s) << 16; return v.f;
}
__device__ __forceinline__ float sigf(float x)  { return 1.f / (1.f + __expf(-x)); }
__device__ __forceinline__ float mytanh(float x){ return 2.f / (1.f + __expf(-2.f * x)) - 1.f; }

// ---------------- constants ----------------
#define BB     16384
#define TT     5
#define F1     300
#define F2     251
#define INF    551
#define KP     576          // padded K for input GEMM (18 k-tiles)
#define G4     512
#define HH     128
#define FLAT   640          // T*H (20 k-tiles)
#define L1N    531
#define L1P    576
#define L1KP   544          // 17 k-tiles
#define L2N    256
#define L3N    64

// ws offsets (bytes)
#define O_WIH  0u
#define O_WHH  589824u
#define O_W1   720896u
#define O_W2   1458176u
#define O_W3   1736704u
#define O_BG   1769472u
#define O_B1   1771520u
#define O_XG   1773824u
#define WS_NEED 85659904u   // O_XG + 81920*512*2 (hs no longer in ws)

// ---------------------------------------------------------------------------
// prep: weights fp32 -> bf16, packed in B-fragment tile order
// ---------------------------------------------------------------------------
__device__ __forceinline__ void pack_b(const float* __restrict__ W, short* __restrict__ dst,
                                       int i, int tpn, int Nsrc, int Ksrc, int ldw)
{
    int tile = i >> 9, rem = i & 511, lane = rem >> 3, jj = rem & 7;
    int tn = tile / tpn, tk = tile - tn * tpn;
    int n = tn * 16 + (lane & 15);
    int k = tk * 32 + (lane >> 4) * 8 + jj;
    float v = (n < Nsrc && k < Ksrc) ? W[n * ldw + k] : 0.f;
    dst[i] = f2bs(v);
}

__global__ void prep_kernel(
    const float* __restrict__ W_ih, const float* __restrict__ W_hh,
    const float* __restrict__ b_ih, const float* __restrict__ b_hh,
    const float* __restrict__ W1,   const float* __restrict__ b1,
    const float* __restrict__ W2,   const float* __restrict__ W3,
    short* __restrict__ Wihp, short* __restrict__ Whhp, float* __restrict__ biasg,
    short* __restrict__ W1p,  float* __restrict__ b1p,  short* __restrict__ W2p,
    short* __restrict__ W3p)
{
    const int N0 = G4 * KP;            // 294912
    const int N1 = N0 + G4 * HH;       // +65536
    const int N2 = N1 + L1P * FLAT;    // +368640
    const int N3 = N2 + L2N * L1KP;    // +139264
    const int N4 = N3 + L3N * L2N;     // +16384
    const int N5 = N4 + G4;
    const int N6 = N5 + L1P;
    const int stride = gridDim.x * blockDim.x;
    for (int i = blockIdx.x * blockDim.x + threadIdx.x; i < N6; i += stride) {
        if (i < N0)      pack_b(W_ih, Wihp, i,       18, G4,  INF, INF);
        else if (i < N1) pack_b(W_hh, Whhp, i - N0,   4, G4,  HH,  HH);
        else if (i < N2) pack_b(W1,   W1p,  i - N1,  20, L1N, FLAT, FLAT);
        else if (i < N3) pack_b(W2,   W2p,  i - N2,  17, L2N, L1N, L1N);
        else if (i < N4) pack_b(W3,   W3p,  i - N3,   8, L3N, L2N, L2N);
        else if (i < N5) { int j = i - N4; biasg[j] = b_ih[j] + b_hh[j]; }
        else             { int j = i - N5; b1p[j] = (j < L1N) ? b1[j] : 0.f; }
    }
}

// ---------------------------------------------------------------------------
// k1_xgemm: R0 VERBATIM (best measured: 127.4 us).
// xg = concat(x)@W_ih^T + bias. M' = t*B + b ordering (81920 rows), BM=64,
// 512 thr. Half-K (288) staged in LDS per barrier-pair -> 144 MFMA/wave
// between barriers. Output in packed C-tiles.
// ---------------------------------------------------------------------------
__device__ __forceinline__ float4 load_chunk4(const float* __restrict__ x1,
                                              const float* __restrict__ x2,
                                              int brow, int t, int c)
{
    if (c < F1) {   // 300 is 4-aligned: no straddle
        return *(const float4*)(x1 + (brow * TT + t) * F1 + c);
    }
    float4 r;
    int base = (brow * TT + t) * F2 + (c - F1);
    r.x = (c + 0 < INF) ? x2[base + 0] : 0.f;
    r.y = (c + 1 < INF) ? x2[base + 1] : 0.f;
    r.z = (c + 2 < INF) ? x2[base + 2] : 0.f;
    r.w = (c + 3 < INF) ? x2[base + 3] : 0.f;
    return r;
}

__global__ __launch_bounds__(512, 4) void k1_xgemm(
    const float* __restrict__ x1, const float* __restrict__ x2,
    const short* __restrict__ Wihp, const float* __restrict__ biasg,
    short* __restrict__ xg)
{
    __shared__ __align__(16) short At[64][296];   // 64 rows x 288 k (+8 pad) = 37.9 KB
    const int tid  = threadIdx.x;
    const int w    = tid >> 6;
    const int lane = tid & 63;
    const int quad = lane >> 4;
    const int c16  = lane & 15;
    const int m0   = blockIdx.x * 64;       // m' = t*B + b
    const int t    = m0 >> 14;              // 64 | 16384 -> whole block same t
    const int bb   = m0 & 16383;

    f32x4 acc[4][4];
#pragma unroll
    for (int mt = 0; mt < 4; ++mt)
#pragma unroll
        for (int nt = 0; nt < 4; ++nt)
            acc[mt][nt] = (f32x4){0.f, 0.f, 0.f, 0.f};

    const int srow  = tid >> 3;            // 0..63
    const int kslot = tid & 7;

    for (int half = 0; half < 2; ++half) {
        __syncthreads();
        {
            int brow = bb + srow;
#pragma unroll
            for (int c = 0; c < 9; ++c) {
                int kl = c * 32 + kslot * 4;
                float4 v = load_chunk4(x1, x2, brow, t, half * 288 + kl);
                short4v s;
                s[0] = f2bs(v.x); s[1] = f2bs(v.y); s[2] = f2bs(v.z); s[3] = f2bs(v.w);
                *(short4v*)&At[srow][kl] = s;
            }
        }
        __syncthreads();
#pragma unroll
        for (int ks = 0; ks < 9; ++ks) {
            short8 a[4];
#pragma unroll
            for (int mt = 0; mt < 4; ++mt)
                a[mt] = *(const short8*)&At[mt * 16 + c16][ks * 32 + quad * 8];
#pragma unroll
            for (int nt = 0; nt < 4; ++nt) {
                int tk = half * 9 + ks;
                short8 b = *(const short8*)&Wihp[(((w * 4 + nt) * 18 + tk) << 9) + lane * 8];
#pragma unroll
                for (int mt = 0; mt < 4; ++mt)
                    acc[mt][nt] = MFMA(a[mt], b, acc[mt][nt]);
            }
        }
    }
    // epilogue: +bias, packed C-tile store (8B/lane, fully coalesced)
#pragma unroll
    for (int nt = 0; nt < 4; ++nt) {
        float bv = biasg[w * 64 + nt * 16 + c16];
#pragma unroll
        for (int mt = 0; mt < 4; ++mt) {
            short4v o;
#pragma unroll
            for (int r = 0; r < 4; ++r) o[r] = f2bs(acc[mt][nt][r] + bv);
            int tm = (m0 >> 4) + mt, tn = w * 4 + nt;
            *(short4v*)&xg[((tm * 32 + tn) << 8) + lane * 4] = o;
        }
    }
}

// ---------------------------------------------------------------------------
// k2mlp: fused LSTM recurrence + MLP + softmax. 32 samples/block, 512 blocks,
// 512 thr. Phase 1 = R0 k2_rec (export -> hsL in LDS instead of global).
// Phase 2 = 8-wave MLP (mh = m-tile 0..1, wn = n-group 0..3) from LDS union.
// LDS: region0 [0,40960): hsL (2x20 A-tiles) | a2[32][264] (after L1).
//      region1 [40960,78336): hb0+hb1 (17408) | a1[32][584] | a3[32][72].
// ---------------------------------------------------------------------------
__global__ __launch_bounds__(512, 2) void k2mlp_kernel(
    const short* __restrict__ Whhp, const short* __restrict__ xg,
    const short* __restrict__ W1p, const float* __restrict__ b1p,
    const short* __restrict__ W2p, const float* __restrict__ b2,
    const short* __restrict__ W3p, const float* __restrict__ b3,
    const float* __restrict__ W4,  const float* __restrict__ b4,
    float* __restrict__ out)
{
    __shared__ __align__(16) char smem[78336];
    short* hsL = (short*)smem;                                   // 40960 B
    short (*a2)[264] = (short (*)[264])smem;                     // 16896 B
    short (*hb0)[136] = (short (*)[136])(smem + 40960);          // 8704 B
    short (*hb1)[136] = (short (*)[136])(smem + 40960 + 8704);   // 8704 B
    short (*a1)[584] = (short (*)[584])(smem + 40960);           // 37376 B
    short (*a3)[72]  = (short (*)[72])(smem + 40960);            // 4608 B

    const int tid  = threadIdx.x;
    const int w    = tid >> 6;
    const int lane = tid & 63;
    const int quad = lane >> 4;
    const int c16  = lane & 15;
    const int btile = blockIdx.x * 2;       // sample-tile base (32 samples)
    const int m0    = blockIdx.x * 32;

    // ---- phase 1: LSTM recurrence (R0 k2_rec, hs -> LDS) ----
    {
        short8 bfr[4][4];                   // [gate][ks]
#pragma unroll
        for (int g = 0; g < 4; ++g)
#pragma unroll
            for (int ks = 0; ks < 4; ++ks)
                bfr[g][ks] = *(const short8*)&Whhp[((((g * 8 + w) * 4) + ks) << 9) + lane * 8];

        float cst[2][4];
#pragma unroll
        for (int mt = 0; mt < 2; ++mt)
#pragma unroll
            for (int r = 0; r < 4; ++r) cst[mt][r] = 0.f;

        const int j = w * 16 + c16;

        for (int t = 0; t < TT; ++t) {
            short4v xq[2][4];
#pragma unroll
            for (int mt = 0; mt < 2; ++mt)
#pragma unroll
                for (int g = 0; g < 4; ++g)
                    xq[mt][g] = *(const short4v*)
                        &xg[((((t << 10) + btile + mt) * 32 + (g * 8 + w)) << 8) + lane * 4];

            f32x4 acc[2][4];
#pragma unroll
            for (int mt = 0; mt < 2; ++mt)
#pragma unroll
                for (int g = 0; g < 4; ++g)
                    acc[mt][g] = (f32x4){0.f, 0.f, 0.f, 0.f};

            if (t > 0) {
                const short (*cur)[136] = ((t - 1) & 1) ? hb1 : hb0;
#pragma unroll
                for (int ks = 0; ks < 4; ++ks) {
                    short8 a[2];
#pragma unroll
                    for (int mt = 0; mt < 2; ++mt)
                        a[mt] = *(const short8*)&cur[mt * 16 + c16][ks * 32 + quad * 8];
#pragma unroll
                    for (int mt = 0; mt < 2; ++mt)
#pragma unroll
                        for (int g = 0; g < 4; ++g)
                            acc[mt][g] = MFMA(a[mt], bfr[g][ks], acc[mt][g]);
                }
            }

            short (*nxt)[136] = (t & 1) ? hb1 : hb0;
#pragma unroll
            for (int mt = 0; mt < 2; ++mt) {
#pragma unroll
                for (int r = 0; r < 4; ++r) {
                    int m = mt * 16 + quad * 4 + r;
                    float gi = acc[mt][0][r] + b2f(xq[mt][0][r]);
                    float gf = acc[mt][1][r] + b2f(xq[mt][1][r]);
                    float gg = acc[mt][2][r] + b2f(xq[mt][2][r]);
                    float go = acc[mt][3][r] + b2f(xq[mt][3][r]);
                    float cn = sigf(gf) * cst[mt][r] + sigf(gi) * mytanh(gg);
                    cst[mt][r] = cn;
                    nxt[m][j] = f2bs(sigf(go) * mytanh(cn));
                }
            }
            __syncthreads();
            // export h_t -> hsL in packed A-tile layout: wave -> (tm=w>>2, kt=w&3)
            {
                int tm = w >> 2, kt = w & 3;
                short8 v = *(const short8*)&nxt[tm * 16 + c16][kt * 32 + quad * 8];
                *(short8*)&hsL[((tm * 20 + t * 4 + kt) << 9) + lane * 8] = v;
            }
        }
    }
    __syncthreads();   // hsL complete; hb dead

    // ---- phase 2: MLP, 8 waves = (mh = m-tile) x (wn = n-group) ----
    const int mh = w >> 2, wn = w & 3;

    // layer 1: K=640 (20 ks), N=576: wn -> 9 n-tiles
    {
        f32x4 acc1[9];
#pragma unroll
        for (int i = 0; i < 9; ++i) acc1[i] = (f32x4){0.f, 0.f, 0.f, 0.f};
#pragma unroll 4
        for (int ks = 0; ks < 20; ++ks) {
            short8 a = *(const short8*)&hsL[((mh * 20 + ks) << 9) + lane * 8];
#pragma unroll
            for (int i = 0; i < 9; ++i) {
                short8 b = *(const short8*)&W1p[(((wn * 9 + i) * 20 + ks) << 9) + lane * 8];
                acc1[i] = MFMA(a, b, acc1[i]);
            }
        }
        __syncthreads();   // all hsL reads done (a1 overlays hb, not hsL; but
                           // keep ordering strict before region writes)
#pragma unroll
        for (int i = 0; i < 9; ++i) {
            int n = (wn * 9 + i) * 16 + c16;
            float bv = b1p[n];
#pragma unroll
            for (int r = 0; r < 4; ++r) {
                int m = mh * 16 + quad * 4 + r;
                float v = acc1[i][r] + bv;
                a1[m][n] = f2bs(v > 0.f ? v : 0.f);
            }
        }
    }
    __syncthreads();

    // layer 2: K=544 (17 ks), N=256: wn -> 4 n-tiles (a2 overlays hsL: dead)
    {
        f32x4 acc2[4];
#pragma unroll
        for (int i = 0; i < 4; ++i) acc2[i] = (f32x4){0.f, 0.f, 0.f, 0.f};
#pragma unroll 4
        for (int ks = 0; ks < 17; ++ks) {
            short8 a = *(const short8*)&a1[mh * 16 + c16][ks * 32 + quad * 8];
#pragma unroll
            for (int i = 0; i < 4; ++i) {
                short8 b = *(const short8*)&W2p[(((wn * 4 + i) * 17 + ks) << 9) + lane * 8];
                acc2[i] = MFMA(a, b, acc2[i]);
            }
        }
#pragma unroll
        for (int i = 0; i < 4; ++i) {
            int n = (wn * 4 + i) * 16 + c16;
            float bv = b2[n];
#pragma unroll
            for (int r = 0; r < 4; ++r) {
                int m = mh * 16 + quad * 4 + r;
                float v = acc2[i][r] + bv;
                a2[m][n] = f2bs(v > 0.f ? v : 0.f);
            }
        }
    }
    __syncthreads();

    // layer 3: K=256 (8 ks), N=64: wn -> 1 n-tile (a3 overlays a1: dead)
    {
        f32x4 acc3 = (f32x4){0.f, 0.f, 0.f, 0.f};
#pragma unroll
        for (int ks = 0; ks < 8; ++ks) {
            short8 a = *(const short8*)&a2[mh * 16 + c16][ks * 32 + quad * 8];
            short8 b = *(const short8*)&W3p[((wn * 8 + ks) << 9) + lane * 8];
            acc3 = MFMA(a, b, acc3);
        }
        __syncthreads();   // all a1 reads (L2) done before a3 write into a1 region
        int n = wn * 16 + c16;
        float bv = b3[n];
#pragma unroll
        for (int r = 0; r < 4; ++r) {
            int m = mh * 16 + quad * 4 + r;
            float v = acc3[r] + bv;
            a3[m][n] = f2bs(v > 0.f ? v : 0.f);
        }
    }
    __syncthreads();

    // layer 4 + softmax on wave 0
    if (tid < 64) {
        int m   = tid >> 1;
        int cls = tid & 1;
        float s = b4[cls];
#pragma unroll 8
        for (int k = 0; k < 64; ++k)
            s += b2f(a3[m][k]) * W4[cls * 64 + k];
        float other = __shfl_xor(s, 1);
        float p = 1.f / (1.f + __expf(other - s));
        out[(m0 + m) * 2 + cls] = p;
    }
}

// ---------------------------------------------------------------------------
extern "C" void kernel_launch(void* const* d_in, const int* in_sizes, int n_in,
                              void* d_out, int out_size, void* d_ws, size_t ws_size,
                              hipStream_t stream)
{
    (void)in_sizes; (void)n_in; (void)out_size;
    if (ws_size < (size_t)WS_NEED) return;

    const float* x1   = (const float*)d_in[0];
    const float* x2   = (const float*)d_in[1];
    const float* W_ih = (const float*)d_in[2];
    const float* W_hh = (const float*)d_in[3];
    const float* b_ih = (const float*)d_in[4];
    const float* b_hh = (const float*)d_in[5];
    const float* W1   = (const float*)d_in[6];
    const float* b1   = (const float*)d_in[7];
    const float* W2   = (const float*)d_in[8];
    const float* b2   = (const float*)d_in[9];
    const float* W3   = (const float*)d_in[10];
    const float* b3   = (const float*)d_in[11];
    const float* W4   = (const float*)d_in[12];
    const float* b4   = (const float*)d_in[13];

    char* ws = (char*)d_ws;
    short* Wihp  = (short*)(ws + O_WIH);
    short* Whhp  = (short*)(ws + O_WHH);
    short* W1p   = (short*)(ws + O_W1);
    short* W2p   = (short*)(ws + O_W2);
    short* W3p   = (short*)(ws + O_W3);
    float* biasg = (float*)(ws + O_BG);
    float* b1p   = (float*)(ws + O_B1);
    short* xg    = (short*)(ws + O_XG);

    prep_kernel<<<3461, 256, 0, stream>>>(W_ih, W_hh, b_ih, b_hh, W1, b1, W2, W3,
                                          Wihp, Whhp, biasg, W1p, b1p, W2p, W3p);
    k1_xgemm<<<1280, 512, 0, stream>>>(x1, x2, Wihp, biasg, xg);
    k2mlp_kernel<<<512, 512, 0, stream>>>(Whhp, xg, W1p, b1p, W2p, b2, W3p, b3,
                                          W4, b4, (float*)d_out);
}